// Round 2
// baseline (1028.085 us; speedup 1.0000x reference)
//
#include <hip/hip_runtime.h>
#include <hip/hip_bf16.h>

#define B_      64
#define S_MAXC  2048
#define PAGE_C  128
#define H_      32
#define KVH_    8
#define HD_     128
#define G_      4        // GQA group = H/KVH
#define CHUNK   256      // tokens per split-K chunk (2 pages)
#define NCHUNK  (S_MAXC / CHUNK)   // 8
#define SCALE_F 0.08838834764831845f
#define LOG2E_F 1.4426950408889634f
#define WS_PART_OFF 64   // floats; flag lives at ws[0]

__device__ __forceinline__ float bfbits2f(unsigned int u) {
    return __builtin_bit_cast(float, u);
}

// ---- dtype-abstracted loads ------------------------------------------------
template<bool FP32>
__device__ __forceinline__ float ld1(const void* base, long idx) {
    if (FP32) return ((const float*)base)[idx];
    return bfbits2f(((unsigned int)((const unsigned short*)base)[idx]) << 16);
}

template<bool FP32>
__device__ __forceinline__ void load8(const void* base, long elem, float o[8]) {
    if (FP32) {
        const float4* p = (const float4*)((const float*)base + elem);
        float4 a = p[0], b = p[1];
        o[0]=a.x; o[1]=a.y; o[2]=a.z; o[3]=a.w;
        o[4]=b.x; o[5]=b.y; o[6]=b.z; o[7]=b.w;
    } else {
        uint4 u = *(const uint4*)((const unsigned short*)base + elem);
        o[0]=bfbits2f(u.x<<16); o[1]=bfbits2f(u.x&0xffff0000u);
        o[2]=bfbits2f(u.y<<16); o[3]=bfbits2f(u.y&0xffff0000u);
        o[4]=bfbits2f(u.z<<16); o[5]=bfbits2f(u.z&0xffff0000u);
        o[6]=bfbits2f(u.w<<16); o[7]=bfbits2f(u.w&0xffff0000u);
    }
}

template<bool FP32>
__device__ __forceinline__ float2 load2(const void* base, long elem) {
    if (FP32) return *(const float2*)((const float*)base + elem);
    unsigned int u = *(const unsigned int*)((const unsigned short*)base + elem);
    return make_float2(bfbits2f(u<<16), bfbits2f(u & 0xffff0000u));
}

// ---------------------------------------------------------------------------
// Detector: classify storage dtype of k_cache. Writes flag (1=fp32, 0=bf16)
// to ws[0]. Low 16 bits of each 32-bit word:
//   packed bf16  -> genuine bf16 value (finite, nonzero for N(0,1))
//   fp32 (bf16-rounded values) -> all zero
//   fp32 (full precision)      -> random; ~0.4% hit bf16 NaN/Inf exponent
// ---------------------------------------------------------------------------
__global__ void detect_dtype(const unsigned int* __restrict__ kc_raw,
                             int* __restrict__ flag) {
    int tid = threadIdx.x;
    int nan_cnt = 0, zero_cnt = 0;
    for (int i = tid; i < 16384; i += 64) {
        unsigned int lo = kc_raw[i] & 0xffffu;
        if ((lo & 0x7f80u) == 0x7f80u) nan_cnt++;
        if (lo == 0u) zero_cnt++;
    }
    #pragma unroll
    for (int off = 32; off > 0; off >>= 1) {
        nan_cnt  += __shfl_xor(nan_cnt,  off);
        zero_cnt += __shfl_xor(zero_cnt, off);
    }
    if (tid == 0)
        *flag = (nan_cnt >= 4 || zero_cnt > 12288) ? 1 : 0;
}

// ---------------------------------------------------------------------------
// Kernel 1: per (b, kvh, chunk) partial flash-decode. 4 waves/block, wave w
// owns tokens [chunk*256 + w*64, +64). Token-per-lane K dot (4 GQA heads
// share the K row), wave softmax, shfl-broadcast P, coalesced V accumulate
// (lane owns dims 2*lane, 2*lane+1). Cross-wave combine in LDS; write
// per-head {acc[128], m, l} partial to ws.
// ---------------------------------------------------------------------------
template<bool FP32>
__global__ __launch_bounds__(256) void attn_partial(
    const int* __restrict__ req_to_token,
    const int* __restrict__ req_pool,
    const int* __restrict__ seq_lens,
    const void* __restrict__ q,
    const void* __restrict__ kc,
    const void* __restrict__ vc,
    const int* __restrict__ flag,
    float* __restrict__ ws)
{
    if (*flag != (FP32 ? 1 : 0)) return;   // wrong-dtype variant: no-op

    const int bk    = blockIdx.x;          // b*KVH + kvh
    const int chunk = blockIdx.y;
    const int b     = bk >> 3;
    const int kvh   = bk & 7;
    const int seq   = seq_lens[b];
    if (chunk * CHUNK >= seq) return;

    __shared__ float q_s[G_ * HD_];
    __shared__ float m_s[4 * G_];
    __shared__ float l_s[4 * G_];
    __shared__ float acc_s[4 * G_ * HD_];

    const int tid = threadIdx.x;

    for (int i = tid; i < G_ * HD_; i += 256) {
        int g = i >> 7, d = i & 127;
        q_s[i] = ld1<FP32>(q, ((long)(b * H_ + kvh * G_ + g) << 7) + d)
               * (SCALE_F * LOG2E_F);
    }
    __syncthreads();

    const int w    = tid >> 6;
    const int lane = tid & 63;
    const int sub_start = chunk * CHUNK + w * 64;
    int n_valid = seq - sub_start;
    if (n_valid > 64) n_valid = 64;
    if (n_valid < 0)  n_valid = 0;

    const int page = sub_start >> 7;       // sub-chunk is within one page
    const int r    = req_pool[b];
    int block_id   = req_to_token[r * S_MAXC + (page << 7)] >> 7;
    block_id = __builtin_amdgcn_readfirstlane(block_id);
    const int sub_off = sub_start & 127;
    const long kvbase = (long)block_id * (PAGE_C * KVH_ * HD_)
                      + (long)sub_off * (KVH_ * HD_)
                      + (long)kvh * HD_;   // element offset

    const bool valid = lane < n_valid;

    // ---- K dot: token-per-lane ----
    float s0 = -1e30f, s1 = -1e30f, s2 = -1e30f, s3 = -1e30f;
    if (valid) {
        const long krow = kvbase + (long)lane * (KVH_ * HD_);
        float a0 = 0.f, a1 = 0.f, a2 = 0.f, a3 = 0.f;
        #pragma unroll
        for (int j = 0; j < 16; j++) {
            float k[8];
            load8<FP32>(kc, krow + j * 8, k);
            const float* q0 = &q_s[0 * HD_ + j * 8];
            const float* q1 = &q_s[1 * HD_ + j * 8];
            const float* q2 = &q_s[2 * HD_ + j * 8];
            const float* q3 = &q_s[3 * HD_ + j * 8];
            #pragma unroll
            for (int e = 0; e < 8; e++) {
                a0 += q0[e] * k[e];
                a1 += q1[e] * k[e];
                a2 += q2[e] * k[e];
                a3 += q3[e] * k[e];
            }
        }
        s0 = a0; s1 = a1; s2 = a2; s3 = a3;
    }

    // ---- wave softmax per head (log2 domain) ----
    float s[G_] = { s0, s1, s2, s3 };
    float p[G_], m[G_], l[G_];
    #pragma unroll
    for (int h = 0; h < G_; h++) {
        float mh = s[h];
        #pragma unroll
        for (int off = 32; off > 0; off >>= 1)
            mh = fmaxf(mh, __shfl_xor(mh, off));
        float ph = valid ? exp2f(s[h] - mh) : 0.f;
        float lh = ph;
        #pragma unroll
        for (int off = 32; off > 0; off >>= 1)
            lh += __shfl_xor(lh, off);
        p[h] = ph; m[h] = mh; l[h] = lh;
    }

    // ---- V accumulate: lane owns dims {2*lane, 2*lane+1} ----
    float acc00 = 0.f, acc01 = 0.f, acc10 = 0.f, acc11 = 0.f;
    float acc20 = 0.f, acc21 = 0.f, acc30 = 0.f, acc31 = 0.f;
    for (int t = 0; t < n_valid; t++) {
        float2 v2 = load2<FP32>(vc, kvbase + (long)t * (KVH_ * HD_) + 2 * lane);
        float p0 = __shfl(p[0], t);
        float p1 = __shfl(p[1], t);
        float p2 = __shfl(p[2], t);
        float p3 = __shfl(p[3], t);
        acc00 += p0 * v2.x; acc01 += p0 * v2.y;
        acc10 += p1 * v2.x; acc11 += p1 * v2.y;
        acc20 += p2 * v2.x; acc21 += p2 * v2.y;
        acc30 += p3 * v2.x; acc31 += p3 * v2.y;
    }

    // ---- cross-wave combine ----
    if (lane == 0) {
        #pragma unroll
        for (int h = 0; h < G_; h++) { m_s[w * G_ + h] = m[h]; l_s[w * G_ + h] = l[h]; }
    }
    *(float2*)&acc_s[(w * G_ + 0) * HD_ + 2 * lane] = make_float2(acc00, acc01);
    *(float2*)&acc_s[(w * G_ + 1) * HD_ + 2 * lane] = make_float2(acc10, acc11);
    *(float2*)&acc_s[(w * G_ + 2) * HD_ + 2 * lane] = make_float2(acc20, acc21);
    *(float2*)&acc_s[(w * G_ + 3) * HD_ + 2 * lane] = make_float2(acc30, acc31);
    __syncthreads();

    float* P = ws + WS_PART_OFF + (long)(bk * NCHUNK + chunk) * (G_ * 130);
    for (int o = tid; o < G_ * HD_; o += 256) {
        int h = o >> 7, d = o & 127;
        float M = fmaxf(fmaxf(m_s[0 * G_ + h], m_s[1 * G_ + h]),
                        fmaxf(m_s[2 * G_ + h], m_s[3 * G_ + h]));
        float val = 0.f;
        #pragma unroll
        for (int w2 = 0; w2 < 4; w2++)
            val += acc_s[(w2 * G_ + h) * HD_ + d] * exp2f(m_s[w2 * G_ + h] - M);
        P[h * 130 + d] = val;
    }
    if (tid < G_) {
        int h = tid;
        float M = fmaxf(fmaxf(m_s[0 * G_ + h], m_s[1 * G_ + h]),
                        fmaxf(m_s[2 * G_ + h], m_s[3 * G_ + h]));
        float L = 0.f;
        #pragma unroll
        for (int w2 = 0; w2 < 4; w2++)
            L += l_s[w2 * G_ + h] * exp2f(m_s[w2 * G_ + h] - M);
        P[h * 130 + 128] = M;
        P[h * 130 + 129] = L;
    }
}

// ---------------------------------------------------------------------------
// Kernel 2: combine <=8 chunk partials per (b,h). Thread d owns output dim d.
// ---------------------------------------------------------------------------
template<bool FP32>
__global__ __launch_bounds__(128) void attn_reduce(
    const int* __restrict__ seq_lens,
    const float* __restrict__ ws,
    const int* __restrict__ flag,
    void* __restrict__ out)
{
    if (*flag != (FP32 ? 1 : 0)) return;

    const int bh = blockIdx.x;           // b*H + h
    const int b  = bh >> 5;
    const int h  = bh & 31;
    const int kvh = h >> 2;
    const int g   = h & 3;
    const int d   = threadIdx.x;
    const int seq = seq_lens[b];
    const int nch = (seq + CHUNK - 1) / CHUNK;

    const float* P0 = ws + WS_PART_OFF
                    + ((long)(b * KVH_ + kvh) * NCHUNK * G_ + g) * 130;
    const int cstride = G_ * 130;

    float M = -1e30f;
    for (int c = 0; c < nch; c++)
        M = fmaxf(M, P0[c * cstride + 128]);

    float L = 0.f, o = 0.f;
    for (int c = 0; c < nch; c++) {
        float wgt = exp2f(P0[c * cstride + 128] - M);
        L += P0[c * cstride + 129] * wgt;
        o += P0[c * cstride + d] * wgt;
    }
    float res = o / L;
    long oidx = (long)(b * H_ + h) * HD_ + d;
    if (FP32) ((float*)out)[oidx] = res;
    else      ((__hip_bfloat16*)out)[oidx] = __float2bfloat16(res);
}

extern "C" void kernel_launch(void* const* d_in, const int* in_sizes, int n_in,
                              void* d_out, int out_size, void* d_ws, size_t ws_size,
                              hipStream_t stream) {
    const int* req_to_token = (const int*)d_in[0];
    const int* req_pool     = (const int*)d_in[1];
    const int* seq_lens     = (const int*)d_in[2];
    const void* q           = d_in[3];
    const void* kc          = d_in[4];
    const void* vc          = d_in[5];
    int*   flag = (int*)d_ws;
    float* wsf  = (float*)d_ws;

    detect_dtype<<<1, 64, 0, stream>>>((const unsigned int*)kc, flag);

    attn_partial<false><<<dim3(B_ * KVH_, NCHUNK), 256, 0, stream>>>(
        req_to_token, req_pool, seq_lens, q, kc, vc, flag, wsf);
    attn_partial<true><<<dim3(B_ * KVH_, NCHUNK), 256, 0, stream>>>(
        req_to_token, req_pool, seq_lens, q, kc, vc, flag, wsf);

    attn_reduce<false><<<dim3(B_ * H_), 128, 0, stream>>>(
        seq_lens, wsf, flag, d_out);
    attn_reduce<true><<<dim3(B_ * H_), 128, 0, stream>>>(
        seq_lens, wsf, flag, d_out);
}